// Round 7
// baseline (3044.377 us; speedup 1.0000x reference)
//
#include <hip/hip_runtime.h>
#include <hip/hip_bf16.h>

// MultiHeadAttention (relative-position).
// Round 7: (a) attn TROWS 16->8 (LDS 49.8->34.6 KB => 4 blocks/CU, 16 waves),
// launch_bounds(256,4); (b) projections moved to split-bf16 MFMA
// (C = Wh*Xh + Wh*Xl + Wl*Xh, error ~2^-16 rel) with prep kernels that
// transpose+split inputs once. attn math unchanged.

#define CH 768
#define NH 12
#define KD 64
#define TT 1024
#define BB 4
#define WIN 10
#define NR 21   // 2*WIN+1

#define SW 4        // waves per attn block
#define SRANGE 256  // s per wave
#define TROWS 8     // K/V tile rows per wave (16->8 for occupancy)

typedef __attribute__((ext_vector_type(8))) short short8;
typedef __attribute__((ext_vector_type(8))) unsigned short ushort8;
typedef __attribute__((ext_vector_type(4))) float f32x4;

#define MFMA_B16(a,b,c) __builtin_amdgcn_mfma_f32_16x16x32_bf16((a),(b),(c),0,0,0)

__device__ __forceinline__ ushort f2bf(float f) {
    unsigned u = __float_as_uint(f);
    u += 0x7FFFu + ((u >> 16) & 1u);     // round-to-nearest-even
    return (ushort)(u >> 16);
}
__device__ __forceinline__ float bf2f(ushort h) {
    return __uint_as_float(((unsigned)h) << 16);
}

// ---------------------------------------------------------------------------
// prep_w: {wq,wk,wv,wo} [768][768] fp32 -> concat [3072][768] split-bf16.
// ---------------------------------------------------------------------------
__global__ __launch_bounds__(256) void prep_w(
    const float* __restrict__ wq, const float* __restrict__ wk,
    const float* __restrict__ wv, const float* __restrict__ wo,
    ushort* __restrict__ Wh, ushort* __restrict__ Wl)
{
    const int mat = blockIdx.y;
    const float* __restrict__ src = (mat==0)?wq:(mat==1)?wk:(mat==2)?wv:wo;
    const size_t idx = ((size_t)blockIdx.x * 256 + threadIdx.x) * 4;
    float4 f = *(const float4*)&src[idx];
    ushort h0=f2bf(f.x), h1=f2bf(f.y), h2=f2bf(f.z), h3=f2bf(f.w);
    ushort l0=f2bf(f.x-bf2f(h0)), l1=f2bf(f.y-bf2f(h1)),
           l2=f2bf(f.z-bf2f(h2)), l3=f2bf(f.w-bf2f(h3));
    const size_t o = (size_t)mat*CH*CH + idx;
    ushort4 hv = {h0,h1,h2,h3}, lv = {l0,l1,l2,l3};
    *(ushort4*)&Wh[o] = hv;
    *(ushort4*)&Wl[o] = lv;
}

// ---------------------------------------------------------------------------
// prep_xT: per batch [CH][TT] fp32 -> [TT][CH] split-bf16 (LDS transpose).
// Used for x and for the attention output.
// ---------------------------------------------------------------------------
__global__ __launch_bounds__(256) void prep_xT(
    const float* __restrict__ in, ushort* __restrict__ oh,
    ushort* __restrict__ ol)
{
    const int b  = blockIdx.z;
    const int c0 = blockIdx.x * 32;   // t
    const int r0 = blockIdx.y * 32;   // channel
    __shared__ float tile[32][33];
    const int tx = threadIdx.x & 31, ty = threadIdx.x >> 5;
    const float* ip = in + (size_t)b * CH * TT;
#pragma unroll
    for (int i = 0; i < 4; i++)
        tile[ty + 8*i][tx] = ip[(size_t)(r0 + ty + 8*i) * TT + c0 + tx];
    __syncthreads();
    ushort* ohp = oh + (size_t)b * TT * CH;
    ushort* olp = ol + (size_t)b * TT * CH;
#pragma unroll
    for (int i = 0; i < 4; i++) {
        float f = tile[tx][ty + 8*i];
        ushort h = f2bf(f), l = f2bf(f - bf2f(h));
        const size_t o = (size_t)(c0 + ty + 8*i) * CH + r0 + tx;
        ohp[o] = h; olp[o] = l;
    }
}

// ---------------------------------------------------------------------------
// Split-bf16 MFMA core: 128x128 tile, K=768, 4 waves (each 64x64 = 4x4 MFMA
// tiles of 16x16x32). A [128 rows][K] and B [128 t-rows][K], both k-contiguous
// per row. LDS pitch 40 bf16 (80 B: 16B-aligned, 2-way banks = free).
// 3 MFMA per tile pair: Ah*Bh + Ah*Bl + Al*Bh.
// ---------------------------------------------------------------------------
__device__ __forceinline__ void mfma_core(
    const ushort* __restrict__ Ahg, const ushort* __restrict__ Alg,
    const ushort* __restrict__ Bhg, const ushort* __restrict__ Blg,
    f32x4 (&acc)[4][4])
{
    __shared__ __align__(16) ushort Ah[128][40], Al[128][40],
                                    Bh[128][40], Bl[128][40];
    const int tid  = threadIdx.x;
    const int srow = tid >> 1;          // staging row 0..127
    const int skh  = (tid & 1) * 16;    // staging k-half
    const int lane = tid & 63;
    const int w    = tid >> 6;
    const int mb   = (w >> 1) * 64;
    const int nb   = (w & 1) * 64;
    const int fr   = lane & 15;         // A row / B col within 16-tile
    const int fk   = (lane >> 4) * 8;   // k offset within 32

    // preload k0 = 0
    size_t go = (size_t)srow * CH + skh;
    ushort8 a0 = *(const ushort8*)&Ahg[go];
    ushort8 a1 = *(const ushort8*)&Ahg[go + 8];
    ushort8 a2 = *(const ushort8*)&Alg[go];
    ushort8 a3 = *(const ushort8*)&Alg[go + 8];
    ushort8 b0 = *(const ushort8*)&Bhg[go];
    ushort8 b1 = *(const ushort8*)&Bhg[go + 8];
    ushort8 b2 = *(const ushort8*)&Blg[go];
    ushort8 b3 = *(const ushort8*)&Blg[go + 8];

    for (int k0 = 0; k0 < CH; k0 += 32) {
        *(ushort8*)&Ah[srow][skh]     = a0;
        *(ushort8*)&Ah[srow][skh + 8] = a1;
        *(ushort8*)&Al[srow][skh]     = a2;
        *(ushort8*)&Al[srow][skh + 8] = a3;
        *(ushort8*)&Bh[srow][skh]     = b0;
        *(ushort8*)&Bh[srow][skh + 8] = b1;
        *(ushort8*)&Bl[srow][skh]     = b2;
        *(ushort8*)&Bl[srow][skh + 8] = b3;
        __syncthreads();
        if (k0 + 32 < CH) {             // issue next-tile loads early
            go = (size_t)srow * CH + (k0 + 32) + skh;
            a0 = *(const ushort8*)&Ahg[go];
            a1 = *(const ushort8*)&Ahg[go + 8];
            a2 = *(const ushort8*)&Alg[go];
            a3 = *(const ushort8*)&Alg[go + 8];
            b0 = *(const ushort8*)&Bhg[go];
            b1 = *(const ushort8*)&Bhg[go + 8];
            b2 = *(const ushort8*)&Blg[go];
            b3 = *(const ushort8*)&Blg[go + 8];
        }
        short8 af[4], alf[4], bhf[4], blf[4];
#pragma unroll
        for (int i = 0; i < 4; i++) {
            af[i]  = *(const short8*)&Ah[mb + i*16 + fr][fk];
            alf[i] = *(const short8*)&Al[mb + i*16 + fr][fk];
            bhf[i] = *(const short8*)&Bh[nb + i*16 + fr][fk];
            blf[i] = *(const short8*)&Bl[nb + i*16 + fr][fk];
        }
#pragma unroll
        for (int i = 0; i < 4; i++)
#pragma unroll
            for (int j = 0; j < 4; j++) {
                acc[i][j] = MFMA_B16(af[i],  bhf[j], acc[i][j]);
                acc[i][j] = MFMA_B16(af[i],  blf[j], acc[i][j]);
                acc[i][j] = MFMA_B16(alf[i], bhf[j], acc[i][j]);
            }
        __syncthreads();
    }
}

// ---------------------------------------------------------------------------
// QKV projection (M = 3*768 concat), output [b][h][t][d] fp32.
// D-frag: col(t)=lane&15, row(m)=(lane>>4)*4+reg  [m89-verified].
// ---------------------------------------------------------------------------
__global__ __launch_bounds__(256) void qkv_mfma(
    const ushort* __restrict__ Wh, const ushort* __restrict__ Wl,
    const float* __restrict__ bq, const float* __restrict__ bk,
    const float* __restrict__ bv,
    const ushort* __restrict__ Xh, const ushort* __restrict__ Xl,
    float* __restrict__ qo, float* __restrict__ ko, float* __restrict__ vo)
{
    const int b  = blockIdx.z;
    const int mt = blockIdx.y;          // 0..17
    const int nt = blockIdx.x;          // 0..7
    const int mrow0 = mt * 128;         // concat row
    const int mat   = mrow0 / CH;       // 0:q 1:k 2:v
    const int mloc0 = mrow0 - mat * CH;

    f32x4 acc[4][4];
#pragma unroll
    for (int i = 0; i < 4; i++)
#pragma unroll
        for (int j = 0; j < 4; j++) acc[i][j] = (f32x4){0.f,0.f,0.f,0.f};

    mfma_core(Wh + (size_t)mrow0 * CH, Wl + (size_t)mrow0 * CH,
              Xh + ((size_t)b * TT + nt * 128) * CH,
              Xl + ((size_t)b * TT + nt * 128) * CH, acc);

    const float* __restrict__ bias = (mat==0)?bq:(mat==1)?bk:bv;
    float* __restrict__ outp       = (mat==0)?qo:(mat==1)?ko:vo;
    const int lane = threadIdx.x & 63;
    const int w    = threadIdx.x >> 6;
    const int mb   = (w >> 1) * 64, nb = (w & 1) * 64;
    const int fr   = lane & 15;
    const int r4   = (lane >> 4) * 4;
    const int h    = (mloc0 + mb) / KD;        // 64-aligned => d base = 0
    float* obase = outp + (size_t)(b * NH + h) * TT * KD;
#pragma unroll
    for (int i = 0; i < 4; i++) {
        const int dd = i * 16 + r4;            // d = dd + r
        float4 bi4 = *(const float4*)&bias[mloc0 + mb + dd];
#pragma unroll
        for (int j = 0; j < 4; j++) {
            const int t = nt * 128 + nb + j * 16 + fr;
            f32x4 a = acc[i][j];
            float4 st = { a[0] + bi4.x, a[1] + bi4.y,
                          a[2] + bi4.z, a[3] + bi4.w };
            *(float4*)&obase[(size_t)t * KD + dd] = st;
        }
    }
}

// ---------------------------------------------------------------------------
// Output projection: out[b][m][t] = wo @ attnT + bo (fp32 final output).
// ---------------------------------------------------------------------------
__global__ __launch_bounds__(256) void out_mfma(
    const ushort* __restrict__ Woh, const ushort* __restrict__ Wol,
    const float* __restrict__ bo,
    const ushort* __restrict__ aTh, const ushort* __restrict__ aTl,
    float* __restrict__ out)
{
    const int b  = blockIdx.z;
    const int mt = blockIdx.y;          // 0..5
    const int nt = blockIdx.x;          // 0..7
    const int mrow0 = mt * 128;

    f32x4 acc[4][4];
#pragma unroll
    for (int i = 0; i < 4; i++)
#pragma unroll
        for (int j = 0; j < 4; j++) acc[i][j] = (f32x4){0.f,0.f,0.f,0.f};

    mfma_core(Woh + (size_t)mrow0 * CH, Wol + (size_t)mrow0 * CH,
              aTh + ((size_t)b * TT + nt * 128) * CH,
              aTl + ((size_t)b * TT + nt * 128) * CH, acc);

    const int lane = threadIdx.x & 63;
    const int w    = threadIdx.x >> 6;
    const int mb   = (w >> 1) * 64, nb = (w & 1) * 64;
    const int fr   = lane & 15;
    const int r4   = (lane >> 4) * 4;
#pragma unroll
    for (int i = 0; i < 4; i++) {
        const int m = mrow0 + mb + i * 16 + r4;
        float4 bi4 = *(const float4*)&bo[m];
#pragma unroll
        for (int j = 0; j < 4; j++) {
            const int t = nt * 128 + nb + j * 16 + fr;
            f32x4 a = acc[i][j];
            float* op = out + ((size_t)b * CH + m) * TT + t;
            op[0]          = a[0] + bi4.x;
            op[TT]         = a[1] + bi4.y;
            op[2 * (size_t)TT] = a[2] + bi4.z;
            op[3 * (size_t)TT] = a[3] + bi4.w;
        }
    }
}

// ---------------------------------------------------------------------------
// Attention (unchanged math): 4 waves/block, lane = query row, wave w owns
// s in [w*256, w*256+256). No-max softmax => partials linear in p.
// TROWS=8 => LDS 34.6 KB => 4 blocks/CU.
// ---------------------------------------------------------------------------
__global__ __launch_bounds__(256, 4) void attn_kernel(
    const float* __restrict__ q, const float* __restrict__ k,
    const float* __restrict__ v, const float* __restrict__ erk,
    const float* __restrict__ erv, float* __restrict__ out)
{
    const int bh = blockIdx.y;          // b*NH + h
    const int b  = bh / NH;
    const int h  = bh % NH;
    const int t0 = blockIdx.x * 64;
    const int tid  = threadIdx.x;
    const int lane = tid & 63;
    const int w    = tid >> 6;
    const int t = t0 + lane;
    const float scale = 0.125f;

    __shared__ __align__(16) float kt[SW][TROWS][KD];   // 8KB (o-red buf too)
    __shared__ __align__(16) float vt[SW][TROWS][KD];   // 8KB
    __shared__ __align__(16) float rel_s[NR][KD];       // erk, then erv
    __shared__ __align__(16) float qlog[NR][64];
    __shared__ __align__(16) float band[NR][64];
    __shared__ __align__(16) float red[2][SW][64];

    for (int idx = tid; idx < NR * KD / 4; idx += 256)
        ((float4*)rel_s)[idx] = ((const float4*)erk)[idx];
    for (int idx = tid; idx < NR * 64; idx += 256)
        ((float*)band)[idx] = 0.0f;

    float qr[KD];
    const float* qrow = q + ((size_t)bh * TT + t) * KD;
#pragma unroll
    for (int i = 0; i < KD / 4; i++) {
        float4 f = *(const float4*)&qrow[i * 4];
        qr[i * 4 + 0] = f.x; qr[i * 4 + 1] = f.y;
        qr[i * 4 + 2] = f.z; qr[i * 4 + 3] = f.w;
    }
    __syncthreads();

    for (int r = w; r < NR; r += SW) {
        float s0 = 0, s1 = 0, s2 = 0, s3 = 0;
#pragma unroll
        for (int i = 0; i < KD / 4; i++) {
            float4 e = *(const float4*)&rel_s[r][i * 4];
            s0 = fmaf(qr[i * 4 + 0], e.x, s0);
            s1 = fmaf(qr[i * 4 + 1], e.y, s1);
            s2 = fmaf(qr[i * 4 + 2], e.z, s2);
            s3 = fmaf(qr[i * 4 + 3], e.w, s3);
        }
        qlog[r][lane] = (s0 + s1) + (s2 + s3);
    }
    __syncthreads();

    for (int idx = tid; idx < NR * KD / 4; idx += 256)
        ((float4*)rel_s)[idx] = ((const float4*)erv)[idx];

    float o[KD];
#pragma unroll
    for (int i = 0; i < KD; i++) o[i] = 0.0f;
    float whi = 0.0f, wlo = 0.0f;

    const int sbase = w * SRANGE;
    for (int j = 0; j < SRANGE / TROWS; j++) {
        const int s0g = sbase + j * TROWS;
        const float* kb = k + ((size_t)bh * TT + s0g) * KD;
        const float* vb = v + ((size_t)bh * TT + s0g) * KD;
        for (int idx = lane; idx < TROWS * KD / 4; idx += 64) {
            ((float4*)kt[w])[idx] = ((const float4*)kb)[idx];
            ((float4*)vt[w])[idx] = ((const float4*)vb)[idx];
        }

#pragma unroll 2
        for (int s = 0; s < TROWS; s++) {
            const int sg = s0g + s;
            float a0 = 0, a1 = 0, a2 = 0, a3 = 0;
#pragma unroll
            for (int i = 0; i < KD / 4; i++) {
                float4 kv = *(const float4*)&kt[w][s][i * 4];
                a0 = fmaf(qr[i * 4 + 0], kv.x, a0);
                a1 = fmaf(qr[i * 4 + 1], kv.y, a1);
                a2 = fmaf(qr[i * 4 + 2], kv.z, a2);
                a3 = fmaf(qr[i * 4 + 3], kv.w, a3);
            }
            const int ru = t - sg + WIN;
            const int rc = min(max(ru, 0), 2 * WIN);
            const float sig = (((a0 + a1) + (a2 + a3)) + qlog[rc][lane]) * scale;
            const float p = __expf(sig);
            whi += (ru <= 0) ? p : 0.0f;
            wlo += (ru >= 2 * WIN) ? p : 0.0f;
            if (ru >= 1 && ru <= 2 * WIN - 1) band[ru][lane] = p;
#pragma unroll
            for (int i = 0; i < KD / 4; i++) {
                float4 vv = *(const float4*)&vt[w][s][i * 4];
                o[i * 4 + 0] = fmaf(p, vv.x, o[i * 4 + 0]);
                o[i * 4 + 1] = fmaf(p, vv.y, o[i * 4 + 1]);
                o[i * 4 + 2] = fmaf(p, vv.z, o[i * 4 + 2]);
                o[i * 4 + 3] = fmaf(p, vv.w, o[i * 4 + 3]);
            }
        }
    }

    red[0][w][lane] = whi;
    red[1][w][lane] = wlo;
    __syncthreads();

    const float whit = red[0][0][lane] + red[0][1][lane]
                     + red[0][2][lane] + red[0][3][lane];
    const float wlot = red[1][0][lane] + red[1][1][lane]
                     + red[1][2][lane] + red[1][3][lane];
    if (w == 0) { band[0][lane] = whit; band[NR - 1][lane] = wlot; }
    __syncthreads();

    float ltot = 0.0f;
#pragma unroll
    for (int r = 0; r < NR; r++) ltot += band[r][lane];
    const float inv = 1.0f / ltot;

    // o-reduction in 8 d-chunks of 8; buffer = kt ([SW][8][64])
    float* ob = out + ((size_t)b * CH + h * KD) * TT + t;
#pragma unroll
    for (int rd = 0; rd < 8; rd++) {
#pragma unroll
        for (int dd = 0; dd < 8; dd++)
            kt[w][dd][lane] = o[rd * 8 + dd];
        __syncthreads();
        for (int dd2 = 0; dd2 < 2; dd2++) {
            const int dloc = w * 2 + dd2;
            const int d = rd * 8 + dloc;
            float sv = kt[0][dloc][lane] + kt[1][dloc][lane]
                     + kt[2][dloc][lane] + kt[3][dloc][lane];
            float rsum = 0.0f;
#pragma unroll
            for (int r = 0; r < NR; r++)
                rsum = fmaf(band[r][lane], rel_s[r][d], rsum);
            ob[(size_t)d * TT] = (sv + rsum) * inv;
        }
        __syncthreads();
    }
}

// ---------------------------------------------------------------------------
extern "C" void kernel_launch(void* const* d_in, const int* in_sizes, int n_in,
                              void* d_out, int out_size, void* d_ws, size_t ws_size,
                              hipStream_t stream)
{
    const float* x   = (const float*)d_in[0];
    const float* wq  = (const float*)d_in[1];
    const float* bq  = (const float*)d_in[2];
    const float* wk  = (const float*)d_in[3];
    const float* bk  = (const float*)d_in[4];
    const float* wv  = (const float*)d_in[5];
    const float* bv  = (const float*)d_in[6];
    const float* wo  = (const float*)d_in[7];
    const float* bo  = (const float*)d_in[8];
    const float* erk = (const float*)d_in[9];
    const float* erv = (const float*)d_in[10];
    float* out = (float*)d_out;

    // workspace layout (bytes); lifetime-disjoint overlays audited:
    //  ab (after qkv) overlays Xh/Xl; aTh/aTl (after attn) overlay qb.
    char* w = (char*)d_ws;
    ushort* Xh = (ushort*)(w + 0);          //  6,291,456
    ushort* Xl = (ushort*)(w + 6291456);    //  6,291,456
    ushort* Wh = (ushort*)(w + 12582912);   //  4,718,592
    ushort* Wl = (ushort*)(w + 17301504);   //  4,718,592
    float*  qb = (float*) (w + 22020096);   // 12,582,912
    float*  kb = (float*) (w + 34603008);   // 12,582,912
    float*  vb = (float*) (w + 47185920);   // 12,582,912 (end 59,768,832)
    float*  ab  = (float*) (w + 0);         // overlays Xh+Xl exactly
    ushort* aTh = (ushort*)(w + 22020096);  // overlays qb
    ushort* aTl = (ushort*)(w + 28311552);

    prep_w<<<dim3(576, 4), 256, 0, stream>>>(wq, wk, wv, wo, Wh, Wl);
    prep_xT<<<dim3(32, 24, 4), 256, 0, stream>>>(x, Xh, Xl);

    qkv_mfma<<<dim3(8, 18, 4), 256, 0, stream>>>(Wh, Wl, bq, bk, bv,
                                                 Xh, Xl, qb, kb, vb);

    attn_kernel<<<dim3(16, 48), 256, 0, stream>>>(qb, kb, vb, erk, erv, ab);

    prep_xT<<<dim3(32, 24, 4), 256, 0, stream>>>(ab, aTh, aTl);

    out_mfma<<<dim3(8, 6, 4), 256, 0, stream>>>(Wh + (size_t)2304 * CH,
                                                Wl + (size_t)2304 * CH,
                                                bo, aTh, aTl, out);
}

// Round 10
// 504.500 us; speedup vs baseline: 6.0344x; 6.0344x over previous
//
#include <hip/hip_runtime.h>
#include <hip/hip_bf16.h>

// MultiHeadAttention (relative-position).
// Round 8 design (resubmit x2; benches timed out at acquisition): recombination
// of the two HW-validated halves:
//  - attn_kernel: round-6 exact (TROWS=16, launch_bounds(256,2), VGPR 124,
//    372 us measured). Round-7 regression root-caused: launch_bounds(256,4)
//    capped VGPR at 128 -> o[64]+qr[64] spilled to scratch (FETCH 9.5 GB).
//  - projections: round-7 split-bf16 MFMA pipeline (~159 us measured,
//    absmax 3.9e-3 passed): C = Wh*Xh + Wh*Xl + Wl*Xh.

#define CH 768
#define NH 12
#define KD 64
#define TT 1024
#define BB 4
#define WIN 10
#define NR 21   // 2*WIN+1

#define SW 4        // waves per attn block
#define SRANGE 256  // s per wave
#define TROWS 16    // K/V tile rows per wave (16 = round-6 known good)

typedef __attribute__((ext_vector_type(8))) short short8;
typedef __attribute__((ext_vector_type(8))) unsigned short ushort8;
typedef __attribute__((ext_vector_type(4))) float f32x4;

#define MFMA_B16(a,b,c) __builtin_amdgcn_mfma_f32_16x16x32_bf16((a),(b),(c),0,0,0)

__device__ __forceinline__ ushort f2bf(float f) {
    unsigned u = __float_as_uint(f);
    u += 0x7FFFu + ((u >> 16) & 1u);     // round-to-nearest-even
    return (ushort)(u >> 16);
}
__device__ __forceinline__ float bf2f(ushort h) {
    return __uint_as_float(((unsigned)h) << 16);
}

// ---------------------------------------------------------------------------
// prep_w: {wq,wk,wv,wo} [768][768] fp32 -> concat [3072][768] split-bf16.
// ---------------------------------------------------------------------------
__global__ __launch_bounds__(256) void prep_w(
    const float* __restrict__ wq, const float* __restrict__ wk,
    const float* __restrict__ wv, const float* __restrict__ wo,
    ushort* __restrict__ Wh, ushort* __restrict__ Wl)
{
    const int mat = blockIdx.y;
    const float* __restrict__ src = (mat==0)?wq:(mat==1)?wk:(mat==2)?wv:wo;
    const size_t idx = ((size_t)blockIdx.x * 256 + threadIdx.x) * 4;
    float4 f = *(const float4*)&src[idx];
    ushort h0=f2bf(f.x), h1=f2bf(f.y), h2=f2bf(f.z), h3=f2bf(f.w);
    ushort l0=f2bf(f.x-bf2f(h0)), l1=f2bf(f.y-bf2f(h1)),
           l2=f2bf(f.z-bf2f(h2)), l3=f2bf(f.w-bf2f(h3));
    const size_t o = (size_t)mat*CH*CH + idx;
    ushort4 hv = {h0,h1,h2,h3}, lv = {l0,l1,l2,l3};
    *(ushort4*)&Wh[o] = hv;
    *(ushort4*)&Wl[o] = lv;
}

// ---------------------------------------------------------------------------
// prep_xT: per batch [CH][TT] fp32 -> [TT][CH] split-bf16 (LDS transpose).
// Used for x and for the attention output.
// ---------------------------------------------------------------------------
__global__ __launch_bounds__(256) void prep_xT(
    const float* __restrict__ in, ushort* __restrict__ oh,
    ushort* __restrict__ ol)
{
    const int b  = blockIdx.z;
    const int c0 = blockIdx.x * 32;   // t
    const int r0 = blockIdx.y * 32;   // channel
    __shared__ float tile[32][33];
    const int tx = threadIdx.x & 31, ty = threadIdx.x >> 5;
    const float* ip = in + (size_t)b * CH * TT;
#pragma unroll
    for (int i = 0; i < 4; i++)
        tile[ty + 8*i][tx] = ip[(size_t)(r0 + ty + 8*i) * TT + c0 + tx];
    __syncthreads();
    ushort* ohp = oh + (size_t)b * TT * CH;
    ushort* olp = ol + (size_t)b * TT * CH;
#pragma unroll
    for (int i = 0; i < 4; i++) {
        float f = tile[tx][ty + 8*i];
        ushort h = f2bf(f), l = f2bf(f - bf2f(h));
        const size_t o = (size_t)(c0 + ty + 8*i) * CH + r0 + tx;
        ohp[o] = h; olp[o] = l;
    }
}

// ---------------------------------------------------------------------------
// Split-bf16 MFMA core: 128x128 tile, K=768, 4 waves (each 64x64 = 4x4 MFMA
// tiles of 16x16x32). A [128 rows][K] and B [128 t-rows][K], both k-contiguous
// per row. LDS pitch 40 bf16 (80 B: 16B-aligned, 2-way banks = free).
// 3 MFMA per tile pair: Ah*Bh + Ah*Bl + Al*Bh.
// ---------------------------------------------------------------------------
__device__ __forceinline__ void mfma_core(
    const ushort* __restrict__ Ahg, const ushort* __restrict__ Alg,
    const ushort* __restrict__ Bhg, const ushort* __restrict__ Blg,
    f32x4 (&acc)[4][4])
{
    __shared__ __align__(16) ushort Ah[128][40], Al[128][40],
                                    Bh[128][40], Bl[128][40];
    const int tid  = threadIdx.x;
    const int srow = tid >> 1;          // staging row 0..127
    const int skh  = (tid & 1) * 16;    // staging k-half
    const int lane = tid & 63;
    const int w    = tid >> 6;
    const int mb   = (w >> 1) * 64;
    const int nb   = (w & 1) * 64;
    const int fr   = lane & 15;         // A row / B col within 16-tile
    const int fk   = (lane >> 4) * 8;   // k offset within 32

    // preload k0 = 0
    size_t go = (size_t)srow * CH + skh;
    ushort8 a0 = *(const ushort8*)&Ahg[go];
    ushort8 a1 = *(const ushort8*)&Ahg[go + 8];
    ushort8 a2 = *(const ushort8*)&Alg[go];
    ushort8 a3 = *(const ushort8*)&Alg[go + 8];
    ushort8 b0 = *(const ushort8*)&Bhg[go];
    ushort8 b1 = *(const ushort8*)&Bhg[go + 8];
    ushort8 b2 = *(const ushort8*)&Blg[go];
    ushort8 b3 = *(const ushort8*)&Blg[go + 8];

    for (int k0 = 0; k0 < CH; k0 += 32) {
        *(ushort8*)&Ah[srow][skh]     = a0;
        *(ushort8*)&Ah[srow][skh + 8] = a1;
        *(ushort8*)&Al[srow][skh]     = a2;
        *(ushort8*)&Al[srow][skh + 8] = a3;
        *(ushort8*)&Bh[srow][skh]     = b0;
        *(ushort8*)&Bh[srow][skh + 8] = b1;
        *(ushort8*)&Bl[srow][skh]     = b2;
        *(ushort8*)&Bl[srow][skh + 8] = b3;
        __syncthreads();
        if (k0 + 32 < CH) {             // issue next-tile loads early
            go = (size_t)srow * CH + (k0 + 32) + skh;
            a0 = *(const ushort8*)&Ahg[go];
            a1 = *(const ushort8*)&Ahg[go + 8];
            a2 = *(const ushort8*)&Alg[go];
            a3 = *(const ushort8*)&Alg[go + 8];
            b0 = *(const ushort8*)&Bhg[go];
            b1 = *(const ushort8*)&Bhg[go + 8];
            b2 = *(const ushort8*)&Blg[go];
            b3 = *(const ushort8*)&Blg[go + 8];
        }
        short8 af[4], alf[4], bhf[4], blf[4];
#pragma unroll
        for (int i = 0; i < 4; i++) {
            af[i]  = *(const short8*)&Ah[mb + i*16 + fr][fk];
            alf[i] = *(const short8*)&Al[mb + i*16 + fr][fk];
            bhf[i] = *(const short8*)&Bh[nb + i*16 + fr][fk];
            blf[i] = *(const short8*)&Bl[nb + i*16 + fr][fk];
        }
#pragma unroll
        for (int i = 0; i < 4; i++)
#pragma unroll
            for (int j = 0; j < 4; j++) {
                acc[i][j] = MFMA_B16(af[i],  bhf[j], acc[i][j]);
                acc[i][j] = MFMA_B16(af[i],  blf[j], acc[i][j]);
                acc[i][j] = MFMA_B16(alf[i], bhf[j], acc[i][j]);
            }
        __syncthreads();
    }
}

// ---------------------------------------------------------------------------
// QKV projection (M = 3*768 concat), output [b][h][t][d] fp32.
// D-frag: col(t)=lane&15, row(m)=(lane>>4)*4+reg  [m89-verified].
// ---------------------------------------------------------------------------
__global__ __launch_bounds__(256) void qkv_mfma(
    const ushort* __restrict__ Wh, const ushort* __restrict__ Wl,
    const float* __restrict__ bq, const float* __restrict__ bk,
    const float* __restrict__ bv,
    const ushort* __restrict__ Xh, const ushort* __restrict__ Xl,
    float* __restrict__ qo, float* __restrict__ ko, float* __restrict__ vo)
{
    const int b  = blockIdx.z;
    const int mt = blockIdx.y;          // 0..17
    const int nt = blockIdx.x;          // 0..7
    const int mrow0 = mt * 128;         // concat row
    const int mat   = mrow0 / CH;       // 0:q 1:k 2:v
    const int mloc0 = mrow0 - mat * CH;

    f32x4 acc[4][4];
#pragma unroll
    for (int i = 0; i < 4; i++)
#pragma unroll
        for (int j = 0; j < 4; j++) acc[i][j] = (f32x4){0.f,0.f,0.f,0.f};

    mfma_core(Wh + (size_t)mrow0 * CH, Wl + (size_t)mrow0 * CH,
              Xh + ((size_t)b * TT + nt * 128) * CH,
              Xl + ((size_t)b * TT + nt * 128) * CH, acc);

    const float* __restrict__ bias = (mat==0)?bq:(mat==1)?bk:bv;
    float* __restrict__ outp       = (mat==0)?qo:(mat==1)?ko:vo;
    const int lane = threadIdx.x & 63;
    const int w    = threadIdx.x >> 6;
    const int mb   = (w >> 1) * 64, nb = (w & 1) * 64;
    const int fr   = lane & 15;
    const int r4   = (lane >> 4) * 4;
    const int h    = (mloc0 + mb) / KD;        // 64-aligned => d base = 0
    float* obase = outp + (size_t)(b * NH + h) * TT * KD;
#pragma unroll
    for (int i = 0; i < 4; i++) {
        const int dd = i * 16 + r4;            // d = dd + r
        float4 bi4 = *(const float4*)&bias[mloc0 + mb + dd];
#pragma unroll
        for (int j = 0; j < 4; j++) {
            const int t = nt * 128 + nb + j * 16 + fr;
            f32x4 a = acc[i][j];
            float4 st = { a[0] + bi4.x, a[1] + bi4.y,
                          a[2] + bi4.z, a[3] + bi4.w };
            *(float4*)&obase[(size_t)t * KD + dd] = st;
        }
    }
}

// ---------------------------------------------------------------------------
// Output projection: out[b][m][t] = wo @ attnT + bo (fp32 final output).
// ---------------------------------------------------------------------------
__global__ __launch_bounds__(256) void out_mfma(
    const ushort* __restrict__ Woh, const ushort* __restrict__ Wol,
    const float* __restrict__ bo,
    const ushort* __restrict__ aTh, const ushort* __restrict__ aTl,
    float* __restrict__ out)
{
    const int b  = blockIdx.z;
    const int mt = blockIdx.y;          // 0..5
    const int nt = blockIdx.x;          // 0..7
    const int mrow0 = mt * 128;

    f32x4 acc[4][4];
#pragma unroll
    for (int i = 0; i < 4; i++)
#pragma unroll
        for (int j = 0; j < 4; j++) acc[i][j] = (f32x4){0.f,0.f,0.f,0.f};

    mfma_core(Woh + (size_t)mrow0 * CH, Wol + (size_t)mrow0 * CH,
              aTh + ((size_t)b * TT + nt * 128) * CH,
              aTl + ((size_t)b * TT + nt * 128) * CH, acc);

    const int lane = threadIdx.x & 63;
    const int w    = threadIdx.x >> 6;
    const int mb   = (w >> 1) * 64, nb = (w & 1) * 64;
    const int fr   = lane & 15;
    const int r4   = (lane >> 4) * 4;
#pragma unroll
    for (int i = 0; i < 4; i++) {
        const int m = mrow0 + mb + i * 16 + r4;
        float4 bi4 = *(const float4*)&bo[m];
#pragma unroll
        for (int j = 0; j < 4; j++) {
            const int t = nt * 128 + nb + j * 16 + fr;
            f32x4 a = acc[i][j];
            float* op = out + ((size_t)b * CH + m) * TT + t;
            op[0]          = a[0] + bi4.x;
            op[TT]         = a[1] + bi4.y;
            op[2 * (size_t)TT] = a[2] + bi4.z;
            op[3 * (size_t)TT] = a[3] + bi4.w;
        }
    }
}

// ---------------------------------------------------------------------------
// Attention (round-6 exact): 4 waves/block, lane = query row, wave w owns
// s in [w*256, w*256+256). No-max softmax => partials linear in p => s-split
// + end reduction. Barrier-free main loop, per-wave private K/V LDS tiles.
// band[r][lane] (r=1..19): unique s per (t,r) => single writer.
// ---------------------------------------------------------------------------
__global__ __launch_bounds__(256, 2) void attn_kernel(
    const float* __restrict__ q, const float* __restrict__ k,
    const float* __restrict__ v, const float* __restrict__ erk,
    const float* __restrict__ erv, float* __restrict__ out)
{
    const int bh = blockIdx.y;          // b*NH + h
    const int b  = bh / NH;
    const int h  = bh % NH;
    const int t0 = blockIdx.x * 64;
    const int tid  = threadIdx.x;
    const int lane = tid & 63;
    const int w    = tid >> 6;          // wave id 0..3
    const int t = t0 + lane;
    const float scale = 0.125f;         // 64^-0.5

    __shared__ __align__(16) float kt[SW][TROWS][KD];   // 16KB (o-red buf too)
    __shared__ __align__(16) float vt[SW][TROWS][KD];   // 16KB
    __shared__ __align__(16) float rel_s[NR][KD];       // erk, then erv
    __shared__ __align__(16) float qlog[NR][64];
    __shared__ __align__(16) float band[NR][64];
    __shared__ __align__(16) float red[2][SW][64];      // whi, wlo partials

    for (int idx = tid; idx < NR * KD / 4; idx += 256)
        ((float4*)rel_s)[idx] = ((const float4*)erk)[idx];
    for (int idx = tid; idx < NR * 64; idx += 256)
        ((float*)band)[idx] = 0.0f;

    float qr[KD];
    const float* qrow = q + ((size_t)bh * TT + t) * KD;
#pragma unroll
    for (int i = 0; i < KD / 4; i++) {
        float4 f = *(const float4*)&qrow[i * 4];
        qr[i * 4 + 0] = f.x; qr[i * 4 + 1] = f.y;
        qr[i * 4 + 2] = f.z; qr[i * 4 + 3] = f.w;
    }
    __syncthreads();   // erk staged, band zeroed

    for (int r = w; r < NR; r += SW) {
        float s0 = 0, s1 = 0, s2 = 0, s3 = 0;
#pragma unroll
        for (int i = 0; i < KD / 4; i++) {
            float4 e = *(const float4*)&rel_s[r][i * 4];
            s0 = fmaf(qr[i * 4 + 0], e.x, s0);
            s1 = fmaf(qr[i * 4 + 1], e.y, s1);
            s2 = fmaf(qr[i * 4 + 2], e.z, s2);
            s3 = fmaf(qr[i * 4 + 3], e.w, s3);
        }
        qlog[r][lane] = (s0 + s1) + (s2 + s3);
    }
    __syncthreads();   // qlog visible; all erk reads done

    for (int idx = tid; idx < NR * KD / 4; idx += 256)
        ((float4*)rel_s)[idx] = ((const float4*)erv)[idx];

    float o[KD];
#pragma unroll
    for (int i = 0; i < KD; i++) o[i] = 0.0f;
    float whi = 0.0f, wlo = 0.0f;

    // ---- barrier-free main loop: wave w owns s in [w*256, w*256+256) ----
    const int sbase = w * SRANGE;
    for (int j = 0; j < SRANGE / TROWS; j++) {
        const int s0g = sbase + j * TROWS;
        const float* kb = k + ((size_t)bh * TT + s0g) * KD;
        const float* vb = v + ((size_t)bh * TT + s0g) * KD;
        for (int idx = lane; idx < TROWS * KD / 4; idx += 64) {
            ((float4*)kt[w])[idx] = ((const float4*)kb)[idx];
            ((float4*)vt[w])[idx] = ((const float4*)vb)[idx];
        }

#pragma unroll 2
        for (int s = 0; s < TROWS; s++) {
            const int sg = s0g + s;
            float a0 = 0, a1 = 0, a2 = 0, a3 = 0;
#pragma unroll
            for (int i = 0; i < KD / 4; i++) {
                float4 kv = *(const float4*)&kt[w][s][i * 4];
                a0 = fmaf(qr[i * 4 + 0], kv.x, a0);
                a1 = fmaf(qr[i * 4 + 1], kv.y, a1);
                a2 = fmaf(qr[i * 4 + 2], kv.z, a2);
                a3 = fmaf(qr[i * 4 + 3], kv.w, a3);
            }
            const int ru = t - sg + WIN;
            const int rc = min(max(ru, 0), 2 * WIN);
            const float sig = (((a0 + a1) + (a2 + a3)) + qlog[rc][lane]) * scale;
            const float p = __expf(sig);
            whi += (ru <= 0) ? p : 0.0f;
            wlo += (ru >= 2 * WIN) ? p : 0.0f;
            if (ru >= 1 && ru <= 2 * WIN - 1) band[ru][lane] = p;
#pragma unroll
            for (int i = 0; i < KD / 4; i++) {
                float4 vv = *(const float4*)&vt[w][s][i * 4];
                o[i * 4 + 0] = fmaf(p, vv.x, o[i * 4 + 0]);
                o[i * 4 + 1] = fmaf(p, vv.y, o[i * 4 + 1]);
                o[i * 4 + 2] = fmaf(p, vv.z, o[i * 4 + 2]);
                o[i * 4 + 3] = fmaf(p, vv.w, o[i * 4 + 3]);
            }
        }
    }

    // ---- cross-wave reduction ----
    red[0][w][lane] = whi;
    red[1][w][lane] = wlo;
    __syncthreads();   // red/band/rel_s(erv) all visible; kt/vt reads done

    const float whit = red[0][0][lane] + red[0][1][lane]
                     + red[0][2][lane] + red[0][3][lane];
    const float wlot = red[1][0][lane] + red[1][1][lane]
                     + red[1][2][lane] + red[1][3][lane];
    if (w == 0) { band[0][lane] = whit; band[NR - 1][lane] = wlot; }
    __syncthreads();

    float ltot = 0.0f;
#pragma unroll
    for (int r = 0; r < NR; r++) ltot += band[r][lane];
    const float inv = 1.0f / ltot;

    // o-reduction in 4 d-chunks of 16; buffer overlays kt (16KB)
    float (*obuf)[TROWS][KD] = kt;   // reuse as [SW][16][64]
    float* ob = out + ((size_t)b * CH + h * KD) * TT + t;
#pragma unroll
    for (int rd = 0; rd < 4; rd++) {
#pragma unroll
        for (int dd = 0; dd < 16; dd++)
            obuf[w][dd][lane] = o[rd * 16 + dd];
        __syncthreads();
        for (int dd2 = 0; dd2 < 4; dd2++) {
            const int dloc = w * 4 + dd2;
            const int d = rd * 16 + dloc;
            float sv = obuf[0][dloc][lane] + obuf[1][dloc][lane]
                     + obuf[2][dloc][lane] + obuf[3][dloc][lane];
            float rsum = 0.0f;
#pragma unroll
            for (int r = 0; r < NR; r++)
                rsum = fmaf(band[r][lane], rel_s[r][d], rsum);
            ob[(size_t)d * TT] = (sv + rsum) * inv;
        }
        __syncthreads();
    }
}

// ---------------------------------------------------------------------------
extern "C" void kernel_launch(void* const* d_in, const int* in_sizes, int n_in,
                              void* d_out, int out_size, void* d_ws, size_t ws_size,
                              hipStream_t stream)
{
    const float* x   = (const float*)d_in[0];
    const float* wq  = (const float*)d_in[1];
    const float* bq  = (const float*)d_in[2];
    const float* wk  = (const float*)d_in[3];
    const float* bk  = (const float*)d_in[4];
    const float* wv  = (const float*)d_in[5];
    const float* bv  = (const float*)d_in[6];
    const float* wo  = (const float*)d_in[7];
    const float* bo  = (const float*)d_in[8];
    const float* erk = (const float*)d_in[9];
    const float* erv = (const float*)d_in[10];
    float* out = (float*)d_out;

    // workspace layout (bytes); lifetime-disjoint overlays audited:
    //  ab (after qkv) overlays Xh/Xl; aTh/aTl (after attn) overlay qb.
    char* w = (char*)d_ws;
    ushort* Xh = (ushort*)(w + 0);          //  6,291,456
    ushort* Xl = (ushort*)(w + 6291456);    //  6,291,456
    ushort* Wh = (ushort*)(w + 12582912);   //  4,718,592
    ushort* Wl = (ushort*)(w + 17301504);   //  4,718,592
    float*  qb = (float*) (w + 22020096);   // 12,582,912
    float*  kb = (float*) (w + 34603008);   // 12,582,912
    float*  vb = (float*) (w + 47185920);   // 12,582,912 (end 59,768,832)
    float*  ab  = (float*) (w + 0);         // overlays Xh+Xl exactly
    ushort* aTh = (ushort*)(w + 22020096);  // overlays qb
    ushort* aTl = (ushort*)(w + 28311552);

    prep_w<<<dim3(576, 4), 256, 0, stream>>>(wq, wk, wv, wo, Wh, Wl);
    prep_xT<<<dim3(32, 24, 4), 256, 0, stream>>>(x, Xh, Xl);

    qkv_mfma<<<dim3(8, 18, 4), 256, 0, stream>>>(Wh, Wl, bq, bk, bv,
                                                 Xh, Xl, qb, kb, vb);

    attn_kernel<<<dim3(16, 48), 256, 0, stream>>>(qb, kb, vb, erk, erv, ab);

    prep_xT<<<dim3(32, 24, 4), 256, 0, stream>>>(ab, aTh, aTl);

    out_mfma<<<dim3(8, 6, 4), 256, 0, stream>>>(Wh + (size_t)2304 * CH,
                                                Wl + (size_t)2304 * CH,
                                                bo, aTh, aTl, out);
}

// Round 13
// 494.366 us; speedup vs baseline: 6.1581x; 1.0205x over previous
//
#include <hip/hip_runtime.h>
#include <hip/hip_bf16.h>

// MultiHeadAttention (relative-position).
// Round 11 design (resubmit x2; benches timed out at acquisition): attn
// occupancy push — 8 waves/block (512 thr), s-range 128/wave, TROWS=8.
// LDS ~51KB/block -> 2 blocks/CU = 16 waves/CU (50%) vs 18.8%. Per-thread body
// identical to the validated round-6 kernel (VGPR ~124, no launch-bounds VGPR
// cap => no spill). GEMM pipeline unchanged (round-7/10 validated split-bf16
// MFMA, ~131 us).

#define CH 768
#define NH 12
#define KD 64
#define TT 1024
#define BB 4
#define WIN 10
#define NR 21   // 2*WIN+1

#define SW 8        // waves per attn block
#define SRANGE 128  // s per wave
#define TROWS 8     // K/V tile rows per wave

typedef __attribute__((ext_vector_type(8))) short short8;
typedef __attribute__((ext_vector_type(8))) unsigned short ushort8;
typedef __attribute__((ext_vector_type(4))) float f32x4;

#define MFMA_B16(a,b,c) __builtin_amdgcn_mfma_f32_16x16x32_bf16((a),(b),(c),0,0,0)

__device__ __forceinline__ ushort f2bf(float f) {
    unsigned u = __float_as_uint(f);
    u += 0x7FFFu + ((u >> 16) & 1u);     // round-to-nearest-even
    return (ushort)(u >> 16);
}
__device__ __forceinline__ float bf2f(ushort h) {
    return __uint_as_float(((unsigned)h) << 16);
}

// ---------------------------------------------------------------------------
// prep_w: {wq,wk,wv,wo} [768][768] fp32 -> concat [3072][768] split-bf16.
// ---------------------------------------------------------------------------
__global__ __launch_bounds__(256) void prep_w(
    const float* __restrict__ wq, const float* __restrict__ wk,
    const float* __restrict__ wv, const float* __restrict__ wo,
    ushort* __restrict__ Wh, ushort* __restrict__ Wl)
{
    const int mat = blockIdx.y;
    const float* __restrict__ src = (mat==0)?wq:(mat==1)?wk:(mat==2)?wv:wo;
    const size_t idx = ((size_t)blockIdx.x * 256 + threadIdx.x) * 4;
    float4 f = *(const float4*)&src[idx];
    ushort h0=f2bf(f.x), h1=f2bf(f.y), h2=f2bf(f.z), h3=f2bf(f.w);
    ushort l0=f2bf(f.x-bf2f(h0)), l1=f2bf(f.y-bf2f(h1)),
           l2=f2bf(f.z-bf2f(h2)), l3=f2bf(f.w-bf2f(h3));
    const size_t o = (size_t)mat*CH*CH + idx;
    ushort4 hv = {h0,h1,h2,h3}, lv = {l0,l1,l2,l3};
    *(ushort4*)&Wh[o] = hv;
    *(ushort4*)&Wl[o] = lv;
}

// ---------------------------------------------------------------------------
// prep_xT: per batch [CH][TT] fp32 -> [TT][CH] split-bf16 (LDS transpose).
// ---------------------------------------------------------------------------
__global__ __launch_bounds__(256) void prep_xT(
    const float* __restrict__ in, ushort* __restrict__ oh,
    ushort* __restrict__ ol)
{
    const int b  = blockIdx.z;
    const int c0 = blockIdx.x * 32;   // t
    const int r0 = blockIdx.y * 32;   // channel
    __shared__ float tile[32][33];
    const int tx = threadIdx.x & 31, ty = threadIdx.x >> 5;
    const float* ip = in + (size_t)b * CH * TT;
#pragma unroll
    for (int i = 0; i < 4; i++)
        tile[ty + 8*i][tx] = ip[(size_t)(r0 + ty + 8*i) * TT + c0 + tx];
    __syncthreads();
    ushort* ohp = oh + (size_t)b * TT * CH;
    ushort* olp = ol + (size_t)b * TT * CH;
#pragma unroll
    for (int i = 0; i < 4; i++) {
        float f = tile[tx][ty + 8*i];
        ushort h = f2bf(f), l = f2bf(f - bf2f(h));
        const size_t o = (size_t)(c0 + ty + 8*i) * CH + r0 + tx;
        ohp[o] = h; olp[o] = l;
    }
}

// ---------------------------------------------------------------------------
// Split-bf16 MFMA core: 128x128 tile, K=768, 4 waves. LDS pitch 40 bf16.
// 3 MFMA per tile pair: Ah*Bh + Ah*Bl + Al*Bh.
// ---------------------------------------------------------------------------
__device__ __forceinline__ void mfma_core(
    const ushort* __restrict__ Ahg, const ushort* __restrict__ Alg,
    const ushort* __restrict__ Bhg, const ushort* __restrict__ Blg,
    f32x4 (&acc)[4][4])
{
    __shared__ __align__(16) ushort Ah[128][40], Al[128][40],
                                    Bh[128][40], Bl[128][40];
    const int tid  = threadIdx.x;
    const int srow = tid >> 1;          // staging row 0..127
    const int skh  = (tid & 1) * 16;    // staging k-half
    const int lane = tid & 63;
    const int w    = tid >> 6;
    const int mb   = (w >> 1) * 64;
    const int nb   = (w & 1) * 64;
    const int fr   = lane & 15;         // A row / B col within 16-tile
    const int fk   = (lane >> 4) * 8;   // k offset within 32

    size_t go = (size_t)srow * CH + skh;
    ushort8 a0 = *(const ushort8*)&Ahg[go];
    ushort8 a1 = *(const ushort8*)&Ahg[go + 8];
    ushort8 a2 = *(const ushort8*)&Alg[go];
    ushort8 a3 = *(const ushort8*)&Alg[go + 8];
    ushort8 b0 = *(const ushort8*)&Bhg[go];
    ushort8 b1 = *(const ushort8*)&Bhg[go + 8];
    ushort8 b2 = *(const ushort8*)&Blg[go];
    ushort8 b3 = *(const ushort8*)&Blg[go + 8];

    for (int k0 = 0; k0 < CH; k0 += 32) {
        *(ushort8*)&Ah[srow][skh]     = a0;
        *(ushort8*)&Ah[srow][skh + 8] = a1;
        *(ushort8*)&Al[srow][skh]     = a2;
        *(ushort8*)&Al[srow][skh + 8] = a3;
        *(ushort8*)&Bh[srow][skh]     = b0;
        *(ushort8*)&Bh[srow][skh + 8] = b1;
        *(ushort8*)&Bl[srow][skh]     = b2;
        *(ushort8*)&Bl[srow][skh + 8] = b3;
        __syncthreads();
        if (k0 + 32 < CH) {             // issue next-tile loads early
            go = (size_t)srow * CH + (k0 + 32) + skh;
            a0 = *(const ushort8*)&Ahg[go];
            a1 = *(const ushort8*)&Ahg[go + 8];
            a2 = *(const ushort8*)&Alg[go];
            a3 = *(const ushort8*)&Alg[go + 8];
            b0 = *(const ushort8*)&Bhg[go];
            b1 = *(const ushort8*)&Bhg[go + 8];
            b2 = *(const ushort8*)&Blg[go];
            b3 = *(const ushort8*)&Blg[go + 8];
        }
        short8 af[4], alf[4], bhf[4], blf[4];
#pragma unroll
        for (int i = 0; i < 4; i++) {
            af[i]  = *(const short8*)&Ah[mb + i*16 + fr][fk];
            alf[i] = *(const short8*)&Al[mb + i*16 + fr][fk];
            bhf[i] = *(const short8*)&Bh[nb + i*16 + fr][fk];
            blf[i] = *(const short8*)&Bl[nb + i*16 + fr][fk];
        }
#pragma unroll
        for (int i = 0; i < 4; i++)
#pragma unroll
            for (int j = 0; j < 4; j++) {
                acc[i][j] = MFMA_B16(af[i],  bhf[j], acc[i][j]);
                acc[i][j] = MFMA_B16(af[i],  blf[j], acc[i][j]);
                acc[i][j] = MFMA_B16(alf[i], bhf[j], acc[i][j]);
            }
        __syncthreads();
    }
}

// ---------------------------------------------------------------------------
// QKV projection (M = 3*768 concat), output [b][h][t][d] fp32.
// ---------------------------------------------------------------------------
__global__ __launch_bounds__(256) void qkv_mfma(
    const ushort* __restrict__ Wh, const ushort* __restrict__ Wl,
    const float* __restrict__ bq, const float* __restrict__ bk,
    const float* __restrict__ bv,
    const ushort* __restrict__ Xh, const ushort* __restrict__ Xl,
    float* __restrict__ qo, float* __restrict__ ko, float* __restrict__ vo)
{
    const int b  = blockIdx.z;
    const int mt = blockIdx.y;          // 0..17
    const int nt = blockIdx.x;          // 0..7
    const int mrow0 = mt * 128;         // concat row
    const int mat   = mrow0 / CH;       // 0:q 1:k 2:v
    const int mloc0 = mrow0 - mat * CH;

    f32x4 acc[4][4];
#pragma unroll
    for (int i = 0; i < 4; i++)
#pragma unroll
        for (int j = 0; j < 4; j++) acc[i][j] = (f32x4){0.f,0.f,0.f,0.f};

    mfma_core(Wh + (size_t)mrow0 * CH, Wl + (size_t)mrow0 * CH,
              Xh + ((size_t)b * TT + nt * 128) * CH,
              Xl + ((size_t)b * TT + nt * 128) * CH, acc);

    const float* __restrict__ bias = (mat==0)?bq:(mat==1)?bk:bv;
    float* __restrict__ outp       = (mat==0)?qo:(mat==1)?ko:vo;
    const int lane = threadIdx.x & 63;
    const int w    = threadIdx.x >> 6;
    const int mb   = (w >> 1) * 64, nb = (w & 1) * 64;
    const int fr   = lane & 15;
    const int r4   = (lane >> 4) * 4;
    const int h    = (mloc0 + mb) / KD;        // 64-aligned => d base = 0
    float* obase = outp + (size_t)(b * NH + h) * TT * KD;
#pragma unroll
    for (int i = 0; i < 4; i++) {
        const int dd = i * 16 + r4;            // d = dd + r
        float4 bi4 = *(const float4*)&bias[mloc0 + mb + dd];
#pragma unroll
        for (int j = 0; j < 4; j++) {
            const int t = nt * 128 + nb + j * 16 + fr;
            f32x4 a = acc[i][j];
            float4 st = { a[0] + bi4.x, a[1] + bi4.y,
                          a[2] + bi4.z, a[3] + bi4.w };
            *(float4*)&obase[(size_t)t * KD + dd] = st;
        }
    }
}

// ---------------------------------------------------------------------------
// Output projection: out[b][m][t] = wo @ attnT + bo (fp32 final output).
// ---------------------------------------------------------------------------
__global__ __launch_bounds__(256) void out_mfma(
    const ushort* __restrict__ Woh, const ushort* __restrict__ Wol,
    const float* __restrict__ bo,
    const ushort* __restrict__ aTh, const ushort* __restrict__ aTl,
    float* __restrict__ out)
{
    const int b  = blockIdx.z;
    const int mt = blockIdx.y;          // 0..5
    const int nt = blockIdx.x;          // 0..7
    const int mrow0 = mt * 128;

    f32x4 acc[4][4];
#pragma unroll
    for (int i = 0; i < 4; i++)
#pragma unroll
        for (int j = 0; j < 4; j++) acc[i][j] = (f32x4){0.f,0.f,0.f,0.f};

    mfma_core(Woh + (size_t)mrow0 * CH, Wol + (size_t)mrow0 * CH,
              aTh + ((size_t)b * TT + nt * 128) * CH,
              aTl + ((size_t)b * TT + nt * 128) * CH, acc);

    const int lane = threadIdx.x & 63;
    const int w    = threadIdx.x >> 6;
    const int mb   = (w >> 1) * 64, nb = (w & 1) * 64;
    const int fr   = lane & 15;
    const int r4   = (lane >> 4) * 4;
#pragma unroll
    for (int i = 0; i < 4; i++) {
        const int m = mrow0 + mb + i * 16 + r4;
        float4 bi4 = *(const float4*)&bo[m];
#pragma unroll
        for (int j = 0; j < 4; j++) {
            const int t = nt * 128 + nb + j * 16 + fr;
            f32x4 a = acc[i][j];
            float* op = out + ((size_t)b * CH + m) * TT + t;
            op[0]          = a[0] + bi4.x;
            op[TT]         = a[1] + bi4.y;
            op[2 * (size_t)TT] = a[2] + bi4.z;
            op[3 * (size_t)TT] = a[3] + bi4.w;
        }
    }
}

// ---------------------------------------------------------------------------
// Attention: 8 waves/block (512 thr), lane = query row (same 64 queries for
// all waves), wave w owns s in [w*128, w*128+128). No-max softmax => partials
// linear in p => s-split + end reduction. Barrier-free main loop, per-wave
// private K/V LDS tiles (TROWS=8). band[r][lane] (r=1..19): unique s per
// (t,r) => single writer. LDS ~51KB => 2 blocks/CU (16 waves) at VGPR<=128.
// ---------------------------------------------------------------------------
__global__ __launch_bounds__(512, 2) void attn_kernel(
    const float* __restrict__ q, const float* __restrict__ k,
    const float* __restrict__ v, const float* __restrict__ erk,
    const float* __restrict__ erv, float* __restrict__ out)
{
    const int bh = blockIdx.y;          // b*NH + h
    const int b  = bh / NH;
    const int h  = bh % NH;
    const int t0 = blockIdx.x * 64;
    const int tid  = threadIdx.x;
    const int lane = tid & 63;
    const int w    = tid >> 6;          // wave id 0..7
    const int t = t0 + lane;
    const float scale = 0.125f;         // 64^-0.5

    __shared__ __align__(16) float kt[SW][TROWS][KD];   // 16KB (o-red buf too)
    __shared__ __align__(16) float vt[SW][TROWS][KD];   // 16KB
    __shared__ __align__(16) float rel_s[NR][KD];       // erk, then erv
    __shared__ __align__(16) float qlog[NR][64];
    __shared__ __align__(16) float band[NR][64];
    __shared__ __align__(16) float red[2][SW][64];      // whi, wlo partials

    for (int idx = tid; idx < NR * KD / 4; idx += 512)
        ((float4*)rel_s)[idx] = ((const float4*)erk)[idx];
    for (int idx = tid; idx < NR * 64; idx += 512)
        ((float*)band)[idx] = 0.0f;

    float qr[KD];
    const float* qrow = q + ((size_t)bh * TT + t) * KD;
#pragma unroll
    for (int i = 0; i < KD / 4; i++) {
        float4 f = *(const float4*)&qrow[i * 4];
        qr[i * 4 + 0] = f.x; qr[i * 4 + 1] = f.y;
        qr[i * 4 + 2] = f.z; qr[i * 4 + 3] = f.w;
    }
    __syncthreads();   // erk staged, band zeroed

    for (int r = w; r < NR; r += SW) {
        float s0 = 0, s1 = 0, s2 = 0, s3 = 0;
#pragma unroll
        for (int i = 0; i < KD / 4; i++) {
            float4 e = *(const float4*)&rel_s[r][i * 4];
            s0 = fmaf(qr[i * 4 + 0], e.x, s0);
            s1 = fmaf(qr[i * 4 + 1], e.y, s1);
            s2 = fmaf(qr[i * 4 + 2], e.z, s2);
            s3 = fmaf(qr[i * 4 + 3], e.w, s3);
        }
        qlog[r][lane] = (s0 + s1) + (s2 + s3);
    }
    __syncthreads();   // qlog visible; all erk reads done

    for (int idx = tid; idx < NR * KD / 4; idx += 512)
        ((float4*)rel_s)[idx] = ((const float4*)erv)[idx];

    float o[KD];
#pragma unroll
    for (int i = 0; i < KD; i++) o[i] = 0.0f;
    float whi = 0.0f, wlo = 0.0f;

    // ---- barrier-free main loop: wave w owns s in [w*128, w*128+128) ----
    const int sbase = w * SRANGE;
    for (int j = 0; j < SRANGE / TROWS; j++) {
        const int s0g = sbase + j * TROWS;
        const float* kb = k + ((size_t)bh * TT + s0g) * KD;
        const float* vb = v + ((size_t)bh * TT + s0g) * KD;
        for (int idx = lane; idx < TROWS * KD / 4; idx += 64) {
            ((float4*)kt[w])[idx] = ((const float4*)kb)[idx];
            ((float4*)vt[w])[idx] = ((const float4*)vb)[idx];
        }

#pragma unroll 2
        for (int s = 0; s < TROWS; s++) {
            const int sg = s0g + s;
            float a0 = 0, a1 = 0, a2 = 0, a3 = 0;
#pragma unroll
            for (int i = 0; i < KD / 4; i++) {
                float4 kv = *(const float4*)&kt[w][s][i * 4];
                a0 = fmaf(qr[i * 4 + 0], kv.x, a0);
                a1 = fmaf(qr[i * 4 + 1], kv.y, a1);
                a2 = fmaf(qr[i * 4 + 2], kv.z, a2);
                a3 = fmaf(qr[i * 4 + 3], kv.w, a3);
            }
            const int ru = t - sg + WIN;
            const int rc = min(max(ru, 0), 2 * WIN);
            const float sig = (((a0 + a1) + (a2 + a3)) + qlog[rc][lane]) * scale;
            const float p = __expf(sig);
            whi += (ru <= 0) ? p : 0.0f;
            wlo += (ru >= 2 * WIN) ? p : 0.0f;
            if (ru >= 1 && ru <= 2 * WIN - 1) band[ru][lane] = p;
#pragma unroll
            for (int i = 0; i < KD / 4; i++) {
                float4 vv = *(const float4*)&vt[w][s][i * 4];
                o[i * 4 + 0] = fmaf(p, vv.x, o[i * 4 + 0]);
                o[i * 4 + 1] = fmaf(p, vv.y, o[i * 4 + 1]);
                o[i * 4 + 2] = fmaf(p, vv.z, o[i * 4 + 2]);
                o[i * 4 + 3] = fmaf(p, vv.w, o[i * 4 + 3]);
            }
        }
    }

    // ---- cross-wave reduction ----
    red[0][w][lane] = whi;
    red[1][w][lane] = wlo;
    __syncthreads();   // red/band/rel_s(erv) all visible; kt/vt reads done

    float whit = 0.0f, wlot = 0.0f;
#pragma unroll
    for (int i = 0; i < SW; i++) { whit += red[0][i][lane]; wlot += red[1][i][lane]; }
    if (w == 0) { band[0][lane] = whit; band[NR - 1][lane] = wlot; }
    __syncthreads();

    float ltot = 0.0f;
#pragma unroll
    for (int r = 0; r < NR; r++) ltot += band[r][lane];
    const float inv = 1.0f / ltot;

    // o-reduction in 8 d-chunks of 8; buffer overlays kt ([SW][8][64] = 16KB)
    float* ob = out + ((size_t)b * CH + h * KD) * TT + t;
#pragma unroll
    for (int rd = 0; rd < 8; rd++) {
#pragma unroll
        for (int dd = 0; dd < TROWS; dd++)
            kt[w][dd][lane] = o[rd * 8 + dd];
        __syncthreads();
        {
            const int dloc = w;                    // 1 d per wave per round
            const int d = rd * 8 + dloc;
            float sv = 0.0f;
#pragma unroll
            for (int i = 0; i < SW; i++) sv += kt[i][dloc][lane];
            float rsum = 0.0f;
#pragma unroll
            for (int r = 0; r < NR; r++)
                rsum = fmaf(band[r][lane], rel_s[r][d], rsum);
            ob[(size_t)d * TT] = (sv + rsum) * inv;
        }
        __syncthreads();
    }
}

// ---------------------------------------------------------------------------
extern "C" void kernel_launch(void* const* d_in, const int* in_sizes, int n_in,
                              void* d_out, int out_size, void* d_ws, size_t ws_size,
                              hipStream_t stream)
{
    const float* x   = (const float*)d_in[0];
    const float* wq  = (const float*)d_in[1];
    const float* bq  = (const float*)d_in[2];
    const float* wk  = (const float*)d_in[3];
    const float* bk  = (const float*)d_in[4];
    const float* wv  = (const float*)d_in[5];
    const float* bv  = (const float*)d_in[6];
    const float* wo  = (const float*)d_in[7];
    const float* bo  = (const float*)d_in[8];
    const float* erk = (const float*)d_in[9];
    const float* erv = (const float*)d_in[10];
    float* out = (float*)d_out;

    // workspace layout (bytes); lifetime-disjoint overlays audited:
    //  ab (after qkv) overlays Xh/Xl; aTh/aTl (after attn) overlay qb.
    char* w = (char*)d_ws;
    ushort* Xh = (ushort*)(w + 0);          //  6,291,456
    ushort* Xl = (ushort*)(w + 6291456);    //  6,291,456
    ushort* Wh = (ushort*)(w + 12582912);   //  4,718,592
    ushort* Wl = (ushort*)(w + 17301504);   //  4,718,592
    float*  qb = (float*) (w + 22020096);   // 12,582,912
    float*  kb = (float*) (w + 34603008);   // 12,582,912
    float*  vb = (float*) (w + 47185920);   // 12,582,912 (end 59,768,832)
    float*  ab  = (float*) (w + 0);         // overlays Xh+Xl exactly
    ushort* aTh = (ushort*)(w + 22020096);  // overlays qb
    ushort* aTl = (ushort*)(w + 28311552);

    prep_w<<<dim3(576, 4), 256, 0, stream>>>(wq, wk, wv, wo, Wh, Wl);
    prep_xT<<<dim3(32, 24, 4), 256, 0, stream>>>(x, Xh, Xl);

    qkv_mfma<<<dim3(8, 18, 4), 256, 0, stream>>>(Wh, Wl, bq, bk, bv,
                                                 Xh, Xl, qb, kb, vb);

    attn_kernel<<<dim3(16, 48), 512, 0, stream>>>(qb, kb, vb, erk, erv, ab);

    prep_xT<<<dim3(32, 24, 4), 256, 0, stream>>>(ab, aTh, aTl);

    out_mfma<<<dim3(8, 6, 4), 256, 0, stream>>>(Wh + (size_t)2304 * CH,
                                                Wl + (size_t)2304 * CH,
                                                bo, aTh, aTl, out);
}